// Round 5
// baseline (54.213 us; speedup 1.0000x reference)
//
#include <hip/hip_runtime.h>

namespace {

constexpr int Cn = 80, NTGT = 200;
constexpr unsigned CH = 85;
constexpr unsigned S0 = 80, S1 = 40, S2 = 20;

constexpr unsigned F0 = 16u * 3u * 80u * 80u * 85u / 4u;   // 6,528,000 float4
constexpr unsigned F1 = 16u * 3u * 40u * 40u * 85u / 4u;   // 1,632,000
constexpr unsigned F2 = 16u * 3u * 20u * 20u * 85u / 4u;   //   408,000

constexpr unsigned BLOCK = 256;
constexpr unsigned B0 = 1500, R0 = 17;  // 1500*17*256 = 6,528,000 exactly
constexpr unsigned B1 = 375,  R1 = 17;  //  375*17*256 = 1,632,000 exactly
constexpr unsigned B2 = 128;
constexpr unsigned CHUNK2 = 3188;       // 128*3188 = 408,064 >= F2
constexpr unsigned NBLK = B0 + B1 + B2; // 2003

constexpr float WO0 = 1.0f / (48.0f * 80.0f * 80.0f);
constexpr float WO1 = 1.0f / (48.0f * 40.0f * 40.0f);
constexpr float WO2 = 1.0f / (48.0f * 20.0f * 20.0f);
constexpr float WC0 = WO0 / 80.0f;
constexpr float WC1 = WO1 / 80.0f;
constexpr float WC2 = WO2 / 80.0f;

// Lean softplus: sp(x) = max(x,0) + log1p(e^{-|x|}).
// 2^{-f} deg-2 (rel err <= 0.25%), log1p deg-3 through origin (abs err <= 1e-3).
// ~15 VALU ops, all FMA-pipe except 2 cvt.
__device__ __forceinline__ float softplus_lean(float x) {
    float s = fminf(fabsf(x) * 1.44269504f, 30.0f);
    int   n = (int)s;
    float f = s - (float)n;
    float q = fmaf(fmaf(0.171122f, f, -0.668647f), f, 0.998651f);   // ~2^{-f}
    float e2 = __int_as_float((127 - n) << 23);                     // 2^{-n}
    float u  = q * e2;                                              // ~e^{-|x|}
    float p  = u * fmaf(fmaf(0.118988f, u, -0.415863f), u, 0.990022f); // ~log1p(u)
    return fmaxf(x, 0.0f) + p;
}

// One float4 whose first element has channel phase c0 (0..84).
// k unrolled with compile-time constants:
//   cls  (5 <= c <= 84):  (c0 - (5-k)) unsigned < 80   [wrap c>=85 lands in box]
//   obj  (c == 4):         c0 == 4-k                   [wrap never yields 4]
// OOB lanes pass c0=0: both tests false for k=0..3.
__device__ __forceinline__ void proc4(const float4 v, unsigned c0,
                                      float& accO, float& accC)
{
    float vals[4] = {v.x, v.y, v.z, v.w};
    #pragma unroll
    for (unsigned k = 0; k < 4; ++k) {
        float sp = softplus_lean(vals[k]);
        accC += ((c0 - (5u - k)) < 80u) ? sp : 0.0f;
        accO += (c0 == (4u - k))        ? sp : 0.0f;
    }
}

__device__ __forceinline__ unsigned wrap85(unsigned c) {
    return (c >= CH) ? c - CH : c;
}

__global__ __launch_bounds__(BLOCK) void yolo_sum_kernel(
    const float* __restrict__ p0, const float* __restrict__ p1,
    const float* __restrict__ p2, float2* __restrict__ part)
{
    unsigned bid = blockIdx.x;
    float accO = 0.0f, accC = 0.0f;
    float wo, wc;

    if (bid < B0 + B1) {
        const float4* P;
        unsigned i;
        if (bid < B0) { P = (const float4*)p0; i = bid * (R0 * BLOCK) + threadIdx.x; wo = WO0; wc = WC0; }
        else          { P = (const float4*)p1; i = (bid - B0) * (R1 * BLOCK) + threadIdx.x; wo = WO1; wc = WC1; }
        unsigned c0 = (i * 4u) % CH;

        #pragma unroll 1
        for (int rb = 0; rb < 2; ++rb) {    // 2 batches x 8 rounds, 8 loads in flight
            float4 v[8];
            #pragma unroll
            for (int k = 0; k < 8; ++k) v[k] = P[i + (unsigned)k * BLOCK];
            #pragma unroll
            for (int k = 0; k < 8; ++k) {
                proc4(v[k], c0, accO, accC);
                c0 = wrap85(c0 + 4u);       // +1024 elements == +4 (mod 85)
            }
            i += 8u * BLOCK;
        }
        proc4(P[i], c0, accO, accC);        // round 17
    } else {
        // seg2: predicated chunk, 13 rounds = 8 + 5
        const float4* P = (const float4*)p2;
        unsigned cbase = (bid - B0 - B1) * CHUNK2;
        unsigned end   = min(cbase + CHUNK2, F2);
        unsigned i     = cbase + threadIdx.x;
        unsigned c0    = (i * 4u) % CH;
        wo = WO2; wc = WC2;

        #pragma unroll 1
        for (int rb = 0; rb < 2; ++rb) {
            float4 v[8] = {};
            int nk = (rb == 0) ? 8 : 5;
            for (int k = 0; k < nk; ++k) {
                unsigned ii = i + (unsigned)k * BLOCK;
                if (ii < end) v[k] = P[ii];
            }
            for (int k = 0; k < nk; ++k) {
                bool inb = (i + (unsigned)k * BLOCK) < end;
                proc4(v[k], inb ? c0 : 0u, accO, accC);
                c0 = wrap85(c0 + 4u);
            }
            i += 8u * BLOCK;
        }
    }

    #pragma unroll
    for (int off = 32; off > 0; off >>= 1) {
        accO += __shfl_down(accO, off);
        accC += __shfl_down(accC, off);
    }
    __shared__ float sO[4], sC[4];
    int lane = threadIdx.x & 63, wv = threadIdx.x >> 6;
    if (lane == 0) { sO[wv] = accO; sC[wv] = accC; }
    __syncthreads();
    if (threadIdx.x == 0)
        part[blockIdx.x] = make_float2(wo * (sO[0] + sO[1] + sO[2] + sO[3]),
                                       wc * (sC[0] + sC[1] + sC[2] + sC[3]));
}

// Merged correction + final (single block): dedup targets per cell via packed
// u32 keys, subtract l*z at hot cells, add block partials, write outputs.
__global__ __launch_bounds__(BLOCK) void yolo_corr_final_kernel(
    const float* __restrict__ p0, const float* __restrict__ p1,
    const float* __restrict__ p2, const float* __restrict__ tgt,
    const float2* __restrict__ part, float* __restrict__ out)
{
    __shared__ unsigned keyO[NTGT], keyC[NTGT];

    int t = threadIdx.x;
    float fb = 0.f, fc = 0.f, fx = 0.f, fy = 0.f;
    bool valid = false;
    if (t < NTGT) {
        fb = tgt[t * 6 + 0];
        fc = tgt[t * 6 + 1];
        fx = tgt[t * 6 + 2];
        fy = tgt[t * 6 + 3];
        valid = (fc < (float)Cn);
    }
    int b  = valid ? (int)fb : 0;
    int cl = valid ? (int)fc : 0;

    const float* preds[3] = {p0, p1, p2};
    const int    SS[3]    = {(int)S0, (int)S1, (int)S2};
    const float  WOs[3]   = {WO0, WO1, WO2};
    const float  WCs[3]   = {WC0, WC1, WC2};

    float accO = 0.0f, accC = 0.0f;

    for (int s = 0; s < 3; ++s) {
        int W = SS[s];
        unsigned myO = 0x80000000u | (unsigned)t;  // unique sentinel
        unsigned myC = myO;
        float vObj = 0.f, vCls = 0.f;
        if (t < NTGT && valid) {
            int gx = min((int)floorf(fx * (float)W), W - 1);
            int gy = min((int)floorf(fy * (float)W), W - 1);
            myO = ((unsigned)b << 14) | ((unsigned)gy << 7) | (unsigned)gx;
            myC = (myO << 7) | (unsigned)cl;
            const float* P = preds[s];
            unsigned cell = ((unsigned)b * 3u * (unsigned)W + (unsigned)gy)
                            * (unsigned)W + (unsigned)gx;   // anchor a=0
            vObj = P[cell * CH + 4u];
            vCls = P[cell * CH + 5u + (unsigned)cl];
        }
        if (t < NTGT) { keyO[t] = myO; keyC[t] = myC; }
        __syncthreads();

        bool uo = true, uc = true;
        int lim = (t < NTGT) ? t : 0;
        #pragma unroll 4
        for (int j = 0; j < lim; ++j) {
            unsigned ko = keyO[j], kc = keyC[j];
            uo = uo && (ko != myO);
            uc = uc && (kc != myC);
        }
        if (t < NTGT && valid) {
            if (uo) accO -= vObj * WOs[s];
            if (uc) accC -= vCls * WCs[s];
        }
        __syncthreads();
    }

    for (unsigned i = threadIdx.x; i < NBLK; i += BLOCK) {
        float2 pp = part[i];
        accO += pp.x; accC += pp.y;
    }

    #pragma unroll
    for (int off = 32; off > 0; off >>= 1) {
        accO += __shfl_down(accO, off);
        accC += __shfl_down(accC, off);
    }
    __shared__ float rO[4], rC[4];
    int lane = threadIdx.x & 63, wv = threadIdx.x >> 6;
    if (lane == 0) { rO[wv] = accO; rC[wv] = accC; }
    __syncthreads();
    if (threadIdx.x == 0) {
        float obj = rO[0] + rO[1] + rO[2] + rO[3];
        float cls = rC[0] + rC[1] + rC[2] + rC[3];
        out[0] = obj + 0.5f * cls;   // BOX_W*0 + OBJ_W*obj + CLS_W*cls
        out[1] = 0.0f;               // total_box
        out[2] = obj;
        out[3] = cls;
    }
}

}  // namespace

extern "C" void kernel_launch(void* const* d_in, const int* in_sizes, int n_in,
                              void* d_out, int out_size, void* d_ws, size_t ws_size,
                              hipStream_t stream)
{
    const float* p0  = (const float*)d_in[0];
    const float* p1  = (const float*)d_in[1];
    const float* p2  = (const float*)d_in[2];
    const float* tgt = (const float*)d_in[3];
    float* out = (float*)d_out;
    float2* part = (float2*)d_ws;   // NBLK partials

    yolo_sum_kernel       <<<NBLK, BLOCK, 0, stream>>>(p0, p1, p2, part);
    yolo_corr_final_kernel<<<1,    BLOCK, 0, stream>>>(p0, p1, p2, tgt, part, out);
}

// Round 6
// 49.400 us; speedup vs baseline: 1.0974x; 1.0974x over previous
//
#include <hip/hip_runtime.h>

namespace {

constexpr int Cn = 80, NTGT = 200;
constexpr unsigned CH = 85;
constexpr unsigned S0 = 80, S1 = 40, S2 = 20;

constexpr unsigned F0 = 16u * 3u * 80u * 80u * 85u / 4u;   // 6,528,000 float4
constexpr unsigned F1 = 16u * 3u * 40u * 40u * 85u / 4u;   // 1,632,000
constexpr unsigned F2 = 16u * 3u * 20u * 20u * 85u / 4u;   //   408,000

constexpr unsigned BLOCK = 256;
constexpr unsigned NBLK  = 2048;                 // 8 blocks/CU exactly
constexpr unsigned STRIDE = NBLK * BLOCK;        // 524,288 float4 / iter
constexpr unsigned CSTEP  = (STRIDE * 4u) % CH;  // 32: channel advance per iter

constexpr float WO0 = 1.0f / (48.0f * 80.0f * 80.0f);
constexpr float WO1 = 1.0f / (48.0f * 40.0f * 40.0f);
constexpr float WO2 = 1.0f / (48.0f * 20.0f * 20.0f);
constexpr float WC0 = WO0 / 80.0f;
constexpr float WC1 = WO1 / 80.0f;
constexpr float WC2 = WO2 / 80.0f;

// Lean softplus: sp(x) = max(x,0) + log1p(e^{-|x|}); ~13 VALU, no v_exp/v_log.
// Valid for |x| <= ~20 (inputs are N(0,1); max |x| over 34M draws ~5.7).
__device__ __forceinline__ float softplus_lean(float x) {
    float s = fminf(fabsf(x) * 1.44269504f, 30.0f);
    int   n = (int)s;
    float f = s - (float)n;
    float q = fmaf(fmaf(0.171122f, f, -0.668647f), f, 0.998651f);      // ~2^{-f}
    float e2 = __int_as_float((127 - n) << 23);                        // 2^{-n}
    float u  = q * e2;                                                 // ~e^{-|x|}
    float p  = u * fmaf(fmaf(0.118988f, u, -0.415863f), u, 0.990022f); // ~log1p(u)
    return fmaxf(x, 0.0f) + p;
}

// One float4 with channel phase c0 (0..84) for its first element.
//   cls (5<=c<=84): (c0-(5-k)) unsigned< 80  [wrapped c>=85 lands in box 0..3]
//   obj (c==4):      c0 == 4-k               [wrap never yields 4]
__device__ __forceinline__ void proc4(const float4 v, unsigned c0,
                                      float& accO, float& accC)
{
    float vals[4] = {v.x, v.y, v.z, v.w};
    #pragma unroll
    for (unsigned k = 0; k < 4; ++k) {
        float sp = softplus_lean(vals[k]);
        accC += ((c0 - (5u - k)) < 80u) ? sp : 0.0f;
        accO += (c0 == (4u - k))        ? sp : 0.0f;
    }
}

__device__ __forceinline__ unsigned wrap85(unsigned c) {
    return (c >= CH) ? c - CH : c;
}

// m13-copy-shaped: grid-stride, ONE float4 load in flight per wave iteration,
// TLP (32 waves/CU) provides the memory concurrency.
__global__ __launch_bounds__(BLOCK) void yolo_sum_kernel(
    const float* __restrict__ p0, const float* __restrict__ p1,
    const float* __restrict__ p2, float2* __restrict__ part)
{
    unsigned tid = blockIdx.x * BLOCK + threadIdx.x;
    unsigned c0_init = (tid * 4u) % CH;

    float totO = 0.0f, totC = 0.0f;

    {   // tensor 0
        const float4* P = (const float4*)p0;
        float accO = 0.0f, accC = 0.0f;
        unsigned c0 = c0_init;
        for (unsigned i = tid; i < F0; i += STRIDE) {
            proc4(P[i], c0, accO, accC);
            c0 = wrap85(c0 + CSTEP);
        }
        totO = fmaf(WO0, accO, totO); totC = fmaf(WC0, accC, totC);
    }
    {   // tensor 1
        const float4* P = (const float4*)p1;
        float accO = 0.0f, accC = 0.0f;
        unsigned c0 = c0_init;
        for (unsigned i = tid; i < F1; i += STRIDE) {
            proc4(P[i], c0, accO, accC);
            c0 = wrap85(c0 + CSTEP);
        }
        totO = fmaf(WO1, accO, totO); totC = fmaf(WC1, accC, totC);
    }
    {   // tensor 2
        const float4* P = (const float4*)p2;
        float accO = 0.0f, accC = 0.0f;
        unsigned c0 = c0_init;
        for (unsigned i = tid; i < F2; i += STRIDE) {
            proc4(P[i], c0, accO, accC);
            c0 = wrap85(c0 + CSTEP);
        }
        totO = fmaf(WO2, accO, totO); totC = fmaf(WC2, accC, totC);
    }

    #pragma unroll
    for (int off = 32; off > 0; off >>= 1) {
        totO += __shfl_down(totO, off);
        totC += __shfl_down(totC, off);
    }
    __shared__ float sO[4], sC[4];
    int lane = threadIdx.x & 63, wv = threadIdx.x >> 6;
    if (lane == 0) { sO[wv] = totO; sC[wv] = totC; }
    __syncthreads();
    if (threadIdx.x == 0)
        part[blockIdx.x] = make_float2(sO[0] + sO[1] + sO[2] + sO[3],
                                       sC[0] + sC[1] + sC[2] + sC[3]);
}

// Merged correction + final (single block): dedup targets per cell via packed
// u32 keys, subtract l*z at hot cells, add block partials, write outputs.
__global__ __launch_bounds__(BLOCK) void yolo_corr_final_kernel(
    const float* __restrict__ p0, const float* __restrict__ p1,
    const float* __restrict__ p2, const float* __restrict__ tgt,
    const float2* __restrict__ part, float* __restrict__ out)
{
    __shared__ unsigned keyO[NTGT], keyC[NTGT];

    int t = threadIdx.x;
    float fb = 0.f, fc = 0.f, fx = 0.f, fy = 0.f;
    bool valid = false;
    if (t < NTGT) {
        fb = tgt[t * 6 + 0];
        fc = tgt[t * 6 + 1];
        fx = tgt[t * 6 + 2];
        fy = tgt[t * 6 + 3];
        valid = (fc < (float)Cn);
    }
    int b  = valid ? (int)fb : 0;
    int cl = valid ? (int)fc : 0;

    const float* preds[3] = {p0, p1, p2};
    const int    SS[3]    = {(int)S0, (int)S1, (int)S2};
    const float  WOs[3]   = {WO0, WO1, WO2};
    const float  WCs[3]   = {WC0, WC1, WC2};

    float accO = 0.0f, accC = 0.0f;

    for (int s = 0; s < 3; ++s) {
        int W = SS[s];
        unsigned myO = 0x80000000u | (unsigned)t;  // unique sentinel
        unsigned myC = myO;
        float vObj = 0.f, vCls = 0.f;
        if (t < NTGT && valid) {
            int gx = min((int)floorf(fx * (float)W), W - 1);
            int gy = min((int)floorf(fy * (float)W), W - 1);
            myO = ((unsigned)b << 14) | ((unsigned)gy << 7) | (unsigned)gx;
            myC = (myO << 7) | (unsigned)cl;
            const float* P = preds[s];
            unsigned cell = ((unsigned)b * 3u * (unsigned)W + (unsigned)gy)
                            * (unsigned)W + (unsigned)gx;   // anchor a=0
            vObj = P[cell * CH + 4u];
            vCls = P[cell * CH + 5u + (unsigned)cl];
        }
        if (t < NTGT) { keyO[t] = myO; keyC[t] = myC; }
        __syncthreads();

        bool uo = true, uc = true;
        int lim = (t < NTGT) ? t : 0;
        #pragma unroll 4
        for (int j = 0; j < lim; ++j) {
            unsigned ko = keyO[j], kc = keyC[j];
            uo = uo && (ko != myO);
            uc = uc && (kc != myC);
        }
        if (t < NTGT && valid) {
            if (uo) accO -= vObj * WOs[s];
            if (uc) accC -= vCls * WCs[s];
        }
        __syncthreads();
    }

    for (unsigned i = threadIdx.x; i < NBLK; i += BLOCK) {
        float2 pp = part[i];
        accO += pp.x; accC += pp.y;
    }

    #pragma unroll
    for (int off = 32; off > 0; off >>= 1) {
        accO += __shfl_down(accO, off);
        accC += __shfl_down(accC, off);
    }
    __shared__ float rO[4], rC[4];
    int lane = threadIdx.x & 63, wv = threadIdx.x >> 6;
    if (lane == 0) { rO[wv] = accO; rC[wv] = accC; }
    __syncthreads();
    if (threadIdx.x == 0) {
        float obj = rO[0] + rO[1] + rO[2] + rO[3];
        float cls = rC[0] + rC[1] + rC[2] + rC[3];
        out[0] = obj + 0.5f * cls;   // BOX_W*0 + OBJ_W*obj + CLS_W*cls
        out[1] = 0.0f;               // total_box
        out[2] = obj;
        out[3] = cls;
    }
}

}  // namespace

extern "C" void kernel_launch(void* const* d_in, const int* in_sizes, int n_in,
                              void* d_out, int out_size, void* d_ws, size_t ws_size,
                              hipStream_t stream)
{
    const float* p0  = (const float*)d_in[0];
    const float* p1  = (const float*)d_in[1];
    const float* p2  = (const float*)d_in[2];
    const float* tgt = (const float*)d_in[3];
    float* out = (float*)d_out;
    float2* part = (float2*)d_ws;   // NBLK partials

    yolo_sum_kernel       <<<NBLK, BLOCK, 0, stream>>>(p0, p1, p2, part);
    yolo_corr_final_kernel<<<1,    BLOCK, 0, stream>>>(p0, p1, p2, tgt, part, out);
}